// Round 1
// baseline (1182.115 us; speedup 1.0000x reference)
//
#include <hip/hip_runtime.h>
#include <hip/hip_bf16.h>

#define D 64          // feature dim == hidden dim
#define GRAPHS 128

// ---------------- gcn_norm / CSR build ----------------

__global__ void deg_kernel(const int* __restrict__ dst, int* __restrict__ deg, int E) {
    int e = blockIdx.x * blockDim.x + threadIdx.x;
    if (e < E) atomicAdd(&deg[dst[e]], 1);
}

__global__ void dinv_kernel(const int* __restrict__ deg, float* __restrict__ dinv, int N) {
    int i = blockIdx.x * blockDim.x + threadIdx.x;
    if (i < N) {
        int d = deg[i];
        dinv[i] = d > 0 ? rsqrtf((float)d) : 0.0f;
    }
}

__global__ void block_sum_kernel(const int* __restrict__ deg, int* __restrict__ bsum, int N) {
    __shared__ int s[256];
    int i = blockIdx.x * 256 + threadIdx.x;
    s[threadIdx.x] = (i < N) ? deg[i] : 0;
    __syncthreads();
    for (int st = 128; st > 0; st >>= 1) {
        if (threadIdx.x < st) s[threadIdx.x] += s[threadIdx.x + st];
        __syncthreads();
    }
    if (threadIdx.x == 0) bsum[blockIdx.x] = s[0];
}

__global__ void scan_bsum_kernel(const int* __restrict__ bsum, int* __restrict__ boff, int NB) {
    if (blockIdx.x == 0 && threadIdx.x == 0) {
        int run = 0;
        for (int i = 0; i < NB; ++i) { boff[i] = run; run += bsum[i]; }
    }
}

__global__ void block_scan_kernel(const int* __restrict__ deg, const int* __restrict__ boff,
                                  int* __restrict__ rowstart, int* __restrict__ cursor, int N) {
    __shared__ int s[256];
    int i = blockIdx.x * 256 + threadIdx.x;
    int v = (i < N) ? deg[i] : 0;
    s[threadIdx.x] = v;
    __syncthreads();
    // Hillis-Steele inclusive scan
    for (int st = 1; st < 256; st <<= 1) {
        int add = (threadIdx.x >= st) ? s[threadIdx.x - st] : 0;
        __syncthreads();
        s[threadIdx.x] += add;
        __syncthreads();
    }
    if (i < N) {
        int excl = boff[blockIdx.x] + s[threadIdx.x] - v;
        rowstart[i] = excl;
        cursor[i]   = excl;
    }
}

// scatter edges into CSR-by-dst; pack (src, wn) as int2 for one 8B load/edge later
__global__ void scatter_kernel(const int* __restrict__ src, const int* __restrict__ dst,
                               const float* __restrict__ dinv, int* __restrict__ cursor,
                               int2* __restrict__ ep, int E) {
    int e = blockIdx.x * blockDim.x + threadIdx.x;
    if (e < E) {
        int d = dst[e], s = src[e];
        float w = dinv[s] * dinv[d];
        int pos = atomicAdd(&cursor[d], 1);
        int2 pk; pk.x = s; pk.y = __float_as_int(w);
        ep[pos] = pk;
    }
}

// ---------------- propagation: one wave per dst node, lane = feature ----------------

__global__ void prop_kernel(const float* __restrict__ in, float* __restrict__ out,
                            const int* __restrict__ rowstart, const int* __restrict__ deg,
                            const int2* __restrict__ ep, int N) {
    int wid = (blockIdx.x * blockDim.x + threadIdx.x) >> 6;
    if (wid >= N) return;
    int lane = threadIdx.x & 63;
    int start = __builtin_amdgcn_readfirstlane(rowstart[wid]);
    int cnt   = __builtin_amdgcn_readfirstlane(deg[wid]);
    float a = 0.0f;
    for (int i = 0; i < cnt; ++i) {
        int2 e = ep[start + i];
        a += __int_as_float(e.y) * in[(size_t)e.x * D + lane];
    }
    out[(size_t)wid * D + lane] = a;
}

// ---------------- GEMM: [N,64] @ [64,64], wave per row, W in LDS ----------------

__global__ void gemm_kernel(const float* __restrict__ in, const float* __restrict__ W,
                            float* __restrict__ acc, int N, int accumulate) {
    __shared__ float Wl[D * D];
    int t = threadIdx.x;
    for (int i = t; i < D * D; i += 256) Wl[i] = W[i];
    __syncthreads();
    int wid = t >> 6, lane = t & 63;
    int n = blockIdx.x * 4 + wid;
    if (n >= N) return;
    float h = in[(size_t)n * D + lane];
    float a = accumulate ? acc[(size_t)n * D + lane] : 0.0f;
#pragma unroll
    for (int d = 0; d < D; ++d) {
        float b = __shfl(h, d, 64);
        a += b * Wl[d * D + lane];   // lanes stride-1: 2-way bank alias = free
    }
    acc[(size_t)n * D + lane] = a;
}

// ---------------- bias + PReLU ----------------

__global__ void bias_prelu_kernel(const float* __restrict__ acc, const float* __restrict__ b,
                                  const float* __restrict__ alpha, float* __restrict__ out, int total) {
    int i = blockIdx.x * blockDim.x + threadIdx.x;
    if (i < total) {
        float v = acc[i] + b[i & (D - 1)];
        float al = alpha[0];
        out[i] = v >= 0.0f ? v : al * v;
    }
}

// ---------------- pooling + critic head (fused) ----------------

__global__ void init_out_kernel(float* __restrict__ out, const float* __restrict__ bout, int n) {
    int i = threadIdx.x;
    if (i < n) out[i] = bout[0];
}

__global__ void pool_kernel(const float* __restrict__ h, const int* __restrict__ batch,
                            const float* __restrict__ Wout, float* __restrict__ out, int N) {
    int wid = (blockIdx.x * blockDim.x + threadIdx.x) >> 6;
    if (wid >= N) return;
    int lane = threadIdx.x & 63;
    float v = h[(size_t)wid * D + lane] * Wout[lane];
#pragma unroll
    for (int st = 32; st > 0; st >>= 1) v += __shfl_down(v, st, 64);
    if (lane == 0) atomicAdd(&out[batch[wid]], v);
}

extern "C" void kernel_launch(void* const* d_in, const int* in_sizes, int n_in,
                              void* d_out, int out_size, void* d_ws, size_t ws_size,
                              hipStream_t stream) {
    const float* x     = (const float*)d_in[0];
    const int*   ei    = (const int*)d_in[1];
    const int*   batch = (const int*)d_in[2];
    const float* W0    = (const float*)d_in[3];
    const float* b0    = (const float*)d_in[4];
    const float* W1    = (const float*)d_in[5];
    const float* b1    = (const float*)d_in[6];
    const float* a0    = (const float*)d_in[7];
    const float* a1    = (const float*)d_in[8];
    const float* Wout  = (const float*)d_in[9];
    const float* bout  = (const float*)d_in[10];

    const int N = in_sizes[0] / D;
    const int E = in_sizes[1] / 2;
    const int* src = ei;
    const int* dst = ei + E;

    // workspace carve (256B aligned)
    size_t off = 0;
    auto alloc = [&](size_t bytes) -> void* {
        void* p = (char*)d_ws + off;
        off = (off + bytes + 255) & ~(size_t)255;
        return p;
    };
    const int NB = (N + 255) / 256;
    int*   deg      = (int*)alloc((size_t)N * 4);
    int*   rowstart = (int*)alloc((size_t)N * 4);
    int*   cursor   = (int*)alloc((size_t)N * 4);
    float* dinv     = (float*)alloc((size_t)N * 4);
    int*   bsum     = (int*)alloc((size_t)NB * 4);
    int*   boff     = (int*)alloc((size_t)NB * 4);
    int2*  epack    = (int2*)alloc((size_t)E * 8);
    float* hA       = (float*)alloc((size_t)N * D * 4);
    float* hB       = (float*)alloc((size_t)N * D * 4);
    float* acc      = (float*)alloc((size_t)N * D * 4);
    float* act0     = (float*)alloc((size_t)N * D * 4);

    const int EB = (E + 255) / 256;        // edge-parallel blocks
    const int NW = (N + 3) / 4;            // wave-per-node blocks (4 waves/block)
    const int NT = (N * D + 255) / 256;    // elementwise blocks

    // --- gcn_norm + CSR build ---
    hipMemsetAsync(deg, 0, (size_t)N * 4, stream);
    deg_kernel<<<EB, 256, 0, stream>>>(dst, deg, E);
    dinv_kernel<<<NB, 256, 0, stream>>>(deg, dinv, N);
    block_sum_kernel<<<NB, 256, 0, stream>>>(deg, bsum, N);
    scan_bsum_kernel<<<1, 1, 0, stream>>>(bsum, boff, NB);
    block_scan_kernel<<<NB, 256, 0, stream>>>(deg, boff, rowstart, cursor, N);
    scatter_kernel<<<EB, 256, 0, stream>>>(src, dst, dinv, cursor, epack, E);

    // --- layer 0: TAGConv(x; W0,b0) -> PReLU(a0) -> act0 ---
    gemm_kernel<<<NW, 256, 0, stream>>>(x, W0, acc, N, 0);
    prop_kernel<<<NW, 256, 0, stream>>>(x, hA, rowstart, deg, epack, N);
    gemm_kernel<<<NW, 256, 0, stream>>>(hA, W0 + 1 * D * D, acc, N, 1);
    prop_kernel<<<NW, 256, 0, stream>>>(hA, hB, rowstart, deg, epack, N);
    gemm_kernel<<<NW, 256, 0, stream>>>(hB, W0 + 2 * D * D, acc, N, 1);
    prop_kernel<<<NW, 256, 0, stream>>>(hB, hA, rowstart, deg, epack, N);
    gemm_kernel<<<NW, 256, 0, stream>>>(hA, W0 + 3 * D * D, acc, N, 1);
    bias_prelu_kernel<<<NT, 256, 0, stream>>>(acc, b0, a0, act0, N * D);

    // --- layer 1: TAGConv(act0; W1,b1) -> PReLU(a1) -> hB ---
    gemm_kernel<<<NW, 256, 0, stream>>>(act0, W1, acc, N, 0);
    prop_kernel<<<NW, 256, 0, stream>>>(act0, hA, rowstart, deg, epack, N);
    gemm_kernel<<<NW, 256, 0, stream>>>(hA, W1 + 1 * D * D, acc, N, 1);
    prop_kernel<<<NW, 256, 0, stream>>>(hA, hB, rowstart, deg, epack, N);
    gemm_kernel<<<NW, 256, 0, stream>>>(hB, W1 + 2 * D * D, acc, N, 1);
    prop_kernel<<<NW, 256, 0, stream>>>(hB, hA, rowstart, deg, epack, N);
    gemm_kernel<<<NW, 256, 0, stream>>>(hA, W1 + 3 * D * D, acc, N, 1);
    bias_prelu_kernel<<<NT, 256, 0, stream>>>(acc, b1, a1, hB, N * D);

    // --- global_add_pool + linear head ---
    init_out_kernel<<<1, 128, 0, stream>>>((float*)d_out, bout, out_size);
    pool_kernel<<<NW, 256, 0, stream>>>(hB, batch, Wout, (float*)d_out, N);
}

// Round 2
// 916.705 us; speedup vs baseline: 1.2895x; 1.2895x over previous
//
#include <hip/hip_runtime.h>
#include <hip/hip_bf16.h>

#define D 64          // feature dim == hidden dim
#define GRAPHS 128

// ---------------- gcn_norm / CSR build ----------------

__global__ void deg_kernel(const int* __restrict__ dst, int* __restrict__ deg, int E) {
    int e = blockIdx.x * blockDim.x + threadIdx.x;
    if (e < E) atomicAdd(&deg[dst[e]], 1);
}

__global__ void dinv_kernel(const int* __restrict__ deg, float* __restrict__ dinv, int N) {
    int i = blockIdx.x * blockDim.x + threadIdx.x;
    if (i < N) {
        int d = deg[i];
        dinv[i] = d > 0 ? rsqrtf((float)d) : 0.0f;
    }
}

__global__ void block_sum_kernel(const int* __restrict__ deg, int* __restrict__ bsum, int N) {
    __shared__ int s[256];
    int i = blockIdx.x * 256 + threadIdx.x;
    s[threadIdx.x] = (i < N) ? deg[i] : 0;
    __syncthreads();
    for (int st = 128; st > 0; st >>= 1) {
        if (threadIdx.x < st) s[threadIdx.x] += s[threadIdx.x + st];
        __syncthreads();
    }
    if (threadIdx.x == 0) bsum[blockIdx.x] = s[0];
}

__global__ void scan_bsum_kernel(const int* __restrict__ bsum, int* __restrict__ boff, int NB) {
    if (blockIdx.x == 0 && threadIdx.x == 0) {
        int run = 0;
        for (int i = 0; i < NB; ++i) { boff[i] = run; run += bsum[i]; }
    }
}

__global__ void block_scan_kernel(const int* __restrict__ deg, const int* __restrict__ boff,
                                  int* __restrict__ rowstart, int* __restrict__ cursor, int N) {
    __shared__ int s[256];
    int i = blockIdx.x * 256 + threadIdx.x;
    int v = (i < N) ? deg[i] : 0;
    s[threadIdx.x] = v;
    __syncthreads();
    for (int st = 1; st < 256; st <<= 1) {
        int add = (threadIdx.x >= st) ? s[threadIdx.x - st] : 0;
        __syncthreads();
        s[threadIdx.x] += add;
        __syncthreads();
    }
    if (i < N) {
        int excl = boff[blockIdx.x] + s[threadIdx.x] - v;
        rowstart[i] = excl;
        cursor[i]   = excl;
    }
}

// scatter edges into CSR-by-dst; pack (src, wn) as int2 for one 8B load/edge later
__global__ void scatter_kernel(const int* __restrict__ src, const int* __restrict__ dst,
                               const float* __restrict__ dinv, int* __restrict__ cursor,
                               int2* __restrict__ ep, int E) {
    int e = blockIdx.x * blockDim.x + threadIdx.x;
    if (e < E) {
        int d = dst[e], s = src[e];
        float w = dinv[s] * dinv[d];
        int pos = atomicAdd(&cursor[d], 1);
        int2 pk; pk.x = s; pk.y = __float_as_int(w);
        ep[pos] = pk;
    }
}

// ---------------- propagation: one wave per dst node, lane = feature ----------------

__global__ void prop_kernel(const float* __restrict__ in, float* __restrict__ out,
                            const int* __restrict__ rowstart, const int* __restrict__ deg,
                            const int2* __restrict__ ep, int N) {
    int wid = (blockIdx.x * blockDim.x + threadIdx.x) >> 6;
    if (wid >= N) return;
    int lane = threadIdx.x & 63;
    int start = __builtin_amdgcn_readfirstlane(rowstart[wid]);
    int cnt   = __builtin_amdgcn_readfirstlane(deg[wid]);
    float a = 0.0f;
    for (int i = 0; i < cnt; ++i) {
        int2 e = ep[start + i];
        a += __int_as_float(e.y) * in[(size_t)e.x * D + lane];
    }
    out[(size_t)wid * D + lane] = a;
}

// ---------------- GEMM: [N,64] @ [64,64], wave per row, W in LDS ----------------

__global__ void gemm_kernel(const float* __restrict__ in, const float* __restrict__ W,
                            float* __restrict__ acc, int N, int accumulate) {
    __shared__ float Wl[D * D];
    int t = threadIdx.x;
    for (int i = t; i < D * D; i += 256) Wl[i] = W[i];
    __syncthreads();
    int wid = t >> 6, lane = t & 63;
    int n = blockIdx.x * 4 + wid;
    if (n >= N) return;
    float h = in[(size_t)n * D + lane];
    float a = accumulate ? acc[(size_t)n * D + lane] : 0.0f;
#pragma unroll
    for (int d = 0; d < D; ++d) {
        float b = __shfl(h, d, 64);
        a += b * Wl[d * D + lane];
    }
    acc[(size_t)n * D + lane] = a;
}

// ---------------- bias + PReLU (layer 0, elementwise) ----------------

__global__ void bias_prelu_kernel(const float* __restrict__ acc, const float* __restrict__ b,
                                  const float* __restrict__ alpha, float* __restrict__ out, int total) {
    int i = blockIdx.x * blockDim.x + threadIdx.x;
    if (i < total) {
        float v = acc[i] + b[i & (D - 1)];
        float al = alpha[0];
        out[i] = v >= 0.0f ? v : al * v;
    }
}

// ---------------- layer-1 epilogue fused with critic dot: s[n] = PReLU(acc[n]+b)·Wout ----------------

__global__ void bias_prelu_dot_kernel(const float* __restrict__ acc, const float* __restrict__ b,
                                      const float* __restrict__ alpha, const float* __restrict__ Wout,
                                      float* __restrict__ s, int N) {
    int wid = (blockIdx.x * blockDim.x + threadIdx.x) >> 6;
    if (wid >= N) return;
    int lane = threadIdx.x & 63;
    float v = acc[(size_t)wid * D + lane] + b[lane];
    float al = alpha[0];
    v = v >= 0.0f ? v : al * v;
    v *= Wout[lane];
#pragma unroll
    for (int st = 32; st > 0; st >>= 1) v += __shfl_down(v, st, 64);
    if (lane == 0) s[wid] = v;
}

// ---------------- segment-sum of per-node scalars into 128 graph bins ----------------

__global__ void init_out_kernel(float* __restrict__ out, const float* __restrict__ bout, int n) {
    int i = threadIdx.x;
    if (i < n) out[i] = bout[0];
}

#define SEG_BLOCKS 128

__global__ void segsum_kernel(const float* __restrict__ s, const int* __restrict__ batch,
                              float* __restrict__ out, int N) {
    __shared__ float bins[GRAPHS];
    for (int i = threadIdx.x; i < GRAPHS; i += 256) bins[i] = 0.0f;
    __syncthreads();
    int chunk = (N + SEG_BLOCKS - 1) / SEG_BLOCKS;
    int lo = blockIdx.x * chunk;
    int hi = min(lo + chunk, N);
    // batch is sorted -> each block's contiguous chunk spans ~2 graphs; LDS atomics are cheap
    for (int i = lo + threadIdx.x; i < hi; i += 256)
        atomicAdd(&bins[batch[i]], s[i]);
    __syncthreads();
    for (int g = threadIdx.x; g < GRAPHS; g += 256) {
        float v = bins[g];
        if (v != 0.0f) atomicAdd(&out[g], v);
    }
}

extern "C" void kernel_launch(void* const* d_in, const int* in_sizes, int n_in,
                              void* d_out, int out_size, void* d_ws, size_t ws_size,
                              hipStream_t stream) {
    const float* x     = (const float*)d_in[0];
    const int*   ei    = (const int*)d_in[1];
    const int*   batch = (const int*)d_in[2];
    const float* W0    = (const float*)d_in[3];
    const float* b0    = (const float*)d_in[4];
    const float* W1    = (const float*)d_in[5];
    const float* b1    = (const float*)d_in[6];
    const float* a0    = (const float*)d_in[7];
    const float* a1    = (const float*)d_in[8];
    const float* Wout  = (const float*)d_in[9];
    const float* bout  = (const float*)d_in[10];

    const int N = in_sizes[0] / D;
    const int E = in_sizes[1] / 2;
    const int* src = ei;
    const int* dst = ei + E;

    size_t off = 0;
    auto alloc = [&](size_t bytes) -> void* {
        void* p = (char*)d_ws + off;
        off = (off + bytes + 255) & ~(size_t)255;
        return p;
    };
    const int NB = (N + 255) / 256;
    int*   deg      = (int*)alloc((size_t)N * 4);
    int*   rowstart = (int*)alloc((size_t)N * 4);
    int*   cursor   = (int*)alloc((size_t)N * 4);
    float* dinv     = (float*)alloc((size_t)N * 4);
    int*   bsum     = (int*)alloc((size_t)NB * 4);
    int*   boff     = (int*)alloc((size_t)NB * 4);
    int2*  epack    = (int2*)alloc((size_t)E * 8);
    float* hA       = (float*)alloc((size_t)N * D * 4);
    float* hB       = (float*)alloc((size_t)N * D * 4);
    float* acc      = (float*)alloc((size_t)N * D * 4);
    float* act0     = (float*)alloc((size_t)N * D * 4);
    float* nscal    = (float*)alloc((size_t)N * 4);

    const int EB = (E + 255) / 256;
    const int NW = (N + 3) / 4;
    const int NT = (N * D + 255) / 256;

    // --- gcn_norm + CSR build ---
    hipMemsetAsync(deg, 0, (size_t)N * 4, stream);
    deg_kernel<<<EB, 256, 0, stream>>>(dst, deg, E);
    dinv_kernel<<<NB, 256, 0, stream>>>(deg, dinv, N);
    block_sum_kernel<<<NB, 256, 0, stream>>>(deg, bsum, N);
    scan_bsum_kernel<<<1, 1, 0, stream>>>(bsum, boff, NB);
    block_scan_kernel<<<NB, 256, 0, stream>>>(deg, boff, rowstart, cursor, N);
    scatter_kernel<<<EB, 256, 0, stream>>>(src, dst, dinv, cursor, epack, E);

    // --- layer 0: TAGConv(x; W0,b0) -> PReLU(a0) -> act0 ---
    gemm_kernel<<<NW, 256, 0, stream>>>(x, W0, acc, N, 0);
    prop_kernel<<<NW, 256, 0, stream>>>(x, hA, rowstart, deg, epack, N);
    gemm_kernel<<<NW, 256, 0, stream>>>(hA, W0 + 1 * D * D, acc, N, 1);
    prop_kernel<<<NW, 256, 0, stream>>>(hA, hB, rowstart, deg, epack, N);
    gemm_kernel<<<NW, 256, 0, stream>>>(hB, W0 + 2 * D * D, acc, N, 1);
    prop_kernel<<<NW, 256, 0, stream>>>(hB, hA, rowstart, deg, epack, N);
    gemm_kernel<<<NW, 256, 0, stream>>>(hA, W0 + 3 * D * D, acc, N, 1);
    bias_prelu_kernel<<<NT, 256, 0, stream>>>(acc, b0, a0, act0, N * D);

    // --- layer 1: TAGConv(act0; W1,b1) -> PReLU(a1) -> scalar dot with Wout ---
    gemm_kernel<<<NW, 256, 0, stream>>>(act0, W1, acc, N, 0);
    prop_kernel<<<NW, 256, 0, stream>>>(act0, hA, rowstart, deg, epack, N);
    gemm_kernel<<<NW, 256, 0, stream>>>(hA, W1 + 1 * D * D, acc, N, 1);
    prop_kernel<<<NW, 256, 0, stream>>>(hA, hB, rowstart, deg, epack, N);
    gemm_kernel<<<NW, 256, 0, stream>>>(hB, W1 + 2 * D * D, acc, N, 1);
    prop_kernel<<<NW, 256, 0, stream>>>(hB, hA, rowstart, deg, epack, N);
    gemm_kernel<<<NW, 256, 0, stream>>>(hA, W1 + 3 * D * D, acc, N, 1);
    bias_prelu_dot_kernel<<<NW, 256, 0, stream>>>(acc, b1, a1, Wout, nscal, N);

    // --- global_add_pool (two-stage, contention-free) ---
    init_out_kernel<<<1, 128, 0, stream>>>((float*)d_out, bout, out_size);
    segsum_kernel<<<SEG_BLOCKS, 256, 0, stream>>>(nscal, batch, (float*)d_out, N);
}

// Round 3
// 641.027 us; speedup vs baseline: 1.8441x; 1.4301x over previous
//
#include <hip/hip_runtime.h>
#include <hip/hip_bf16.h>

#define D 64          // feature dim == hidden dim
#define GRAPHS 128

// ---------------- gcn_norm / CSR build ----------------

__global__ void deg_kernel(const int* __restrict__ dst, int* __restrict__ deg, int E) {
    int e = blockIdx.x * blockDim.x + threadIdx.x;
    if (e < E) atomicAdd(&deg[dst[e]], 1);
}

__global__ void dinv_kernel(const int* __restrict__ deg, float* __restrict__ dinv, int N) {
    int i = blockIdx.x * blockDim.x + threadIdx.x;
    if (i < N) {
        int d = deg[i];
        dinv[i] = d > 0 ? rsqrtf((float)d) : 0.0f;
    }
}

__global__ void block_sum_kernel(const int* __restrict__ deg, int* __restrict__ bsum, int N) {
    __shared__ int s[256];
    int i = blockIdx.x * 256 + threadIdx.x;
    s[threadIdx.x] = (i < N) ? deg[i] : 0;
    __syncthreads();
    for (int st = 128; st > 0; st >>= 1) {
        if (threadIdx.x < st) s[threadIdx.x] += s[threadIdx.x + st];
        __syncthreads();
    }
    if (threadIdx.x == 0) bsum[blockIdx.x] = s[0];
}

// parallel exclusive scan of block sums (NB <= 256 fast path; serial fallback otherwise)
__global__ void scan_bsum_kernel(const int* __restrict__ bsum, int* __restrict__ boff, int NB) {
    if (NB <= 256) {
        __shared__ int s[256];
        int i = threadIdx.x;
        int v = (i < NB) ? bsum[i] : 0;
        s[i] = v;
        __syncthreads();
        for (int st = 1; st < 256; st <<= 1) {
            int add = (i >= st) ? s[i - st] : 0;
            __syncthreads();
            s[i] += add;
            __syncthreads();
        }
        if (i < NB) boff[i] = s[i] - v;
    } else if (threadIdx.x == 0) {
        int run = 0;
        for (int i = 0; i < NB; ++i) { boff[i] = run; run += bsum[i]; }
    }
}

__global__ void block_scan_kernel(const int* __restrict__ deg, const int* __restrict__ boff,
                                  int* __restrict__ rowstart, int* __restrict__ cursor, int N) {
    __shared__ int s[256];
    int i = blockIdx.x * 256 + threadIdx.x;
    int v = (i < N) ? deg[i] : 0;
    s[threadIdx.x] = v;
    __syncthreads();
    for (int st = 1; st < 256; st <<= 1) {
        int add = (threadIdx.x >= st) ? s[threadIdx.x - st] : 0;
        __syncthreads();
        s[threadIdx.x] += add;
        __syncthreads();
    }
    if (i < N) {
        int excl = boff[blockIdx.x] + s[threadIdx.x] - v;
        rowstart[i] = excl;
        cursor[i]   = excl;
    }
}

// scatter edges into CSR-by-dst; pack (src, wn) as int2 for one 8B load/edge later
__global__ void scatter_kernel(const int* __restrict__ src, const int* __restrict__ dst,
                               const float* __restrict__ dinv, int* __restrict__ cursor,
                               int2* __restrict__ ep, int E) {
    int e = blockIdx.x * blockDim.x + threadIdx.x;
    if (e < E) {
        int d = dst[e], s = src[e];
        float w = dinv[s] * dinv[d];
        int pos = atomicAdd(&cursor[d], 1);
        int2 pk; pk.x = s; pk.y = __float_as_int(w);
        ep[pos] = pk;
    }
}

// ---------------- fused propagation + GEMM epilogue ----------------
// Wave per dst node, lane = feature. Gathers h_next = norm_adj @ in, then applies
// the 64x64 weight via readlane-broadcast (VALU) x LDS-staged W column (2-way bank
// alias = free). MODE:
//   0: first hop of a layer:  acc  = in_own@WA + h@WB ; write h, acc
//   1: middle hop:            acc += h@WB             ; write h, acc
//   2: last hop, layer 0:     act0 = prelu(acc + h@WB + bias)        (write act0 only)
//   3: last hop, layer 1:     nscal = prelu(acc + h@WB + bias)·Wout  (write nscal only)

#define ROWS_PER_BLOCK 16   // 1024 threads: amortizes W staging across 16 rows

template<int MODE>
__global__ void prop_fused_kernel(const float* __restrict__ in, float* __restrict__ hout,
                                  float* __restrict__ acc,
                                  const float* __restrict__ WA, const float* __restrict__ WB,
                                  const float* __restrict__ bias, const float* __restrict__ alpha,
                                  const float* __restrict__ Wout, float* __restrict__ nscal,
                                  const int* __restrict__ rowstart, const int* __restrict__ deg,
                                  const int2* __restrict__ ep, int N) {
    extern __shared__ float smem[];
    float* WBl = smem;             // hop weight (always)
    float* WAl = smem + D * D;     // k=0 weight (MODE 0 only)

    for (int i = threadIdx.x; i < D * D; i += blockDim.x) WBl[i] = WB[i];
    if (MODE == 0)
        for (int i = threadIdx.x; i < D * D; i += blockDim.x) WAl[i] = WA[i];
    __syncthreads();

    int wid = blockIdx.x * ROWS_PER_BLOCK + (threadIdx.x >> 6);
    if (wid >= N) return;
    int lane = threadIdx.x & 63;

    int start = __builtin_amdgcn_readfirstlane(rowstart[wid]);
    int cnt   = __builtin_amdgcn_readfirstlane(deg[wid]);

    // ---- gather: lane-cooperative edge load, readlane broadcast, pipelined gathers ----
    float a = 0.0f;
    for (int base = 0; base < cnt; base += 64) {
        int m = min(cnt - base, 64);
        int2 e = make_int2(0, 0);
        if (lane < m) e = ep[start + base + lane];
        for (int i = 0; i < m; ++i) {
            int sidx = __builtin_amdgcn_readlane(e.x, i);
            int wbit = __builtin_amdgcn_readlane(e.y, i);
            a = fmaf(__int_as_float(wbit), in[(size_t)sidx * D + lane], a);
        }
    }

    // ---- epilogue: acc row ----
    float accv;
    if (MODE == 0) {
        float own = in[(size_t)wid * D + lane];
        float p0 = 0.f, p1 = 0.f, p2 = 0.f, p3 = 0.f;
#pragma unroll
        for (int d = 0; d < D; d += 4) {
            p0 = fmaf(__int_as_float(__builtin_amdgcn_readlane(__float_as_int(own), d + 0)), WAl[(d + 0) * D + lane], p0);
            p1 = fmaf(__int_as_float(__builtin_amdgcn_readlane(__float_as_int(own), d + 1)), WAl[(d + 1) * D + lane], p1);
            p2 = fmaf(__int_as_float(__builtin_amdgcn_readlane(__float_as_int(own), d + 2)), WAl[(d + 2) * D + lane], p2);
            p3 = fmaf(__int_as_float(__builtin_amdgcn_readlane(__float_as_int(own), d + 3)), WAl[(d + 3) * D + lane], p3);
        }
        accv = (p0 + p1) + (p2 + p3);
    } else {
        accv = acc[(size_t)wid * D + lane];
    }
    {
        float p0 = 0.f, p1 = 0.f, p2 = 0.f, p3 = 0.f;
#pragma unroll
        for (int d = 0; d < D; d += 4) {
            p0 = fmaf(__int_as_float(__builtin_amdgcn_readlane(__float_as_int(a), d + 0)), WBl[(d + 0) * D + lane], p0);
            p1 = fmaf(__int_as_float(__builtin_amdgcn_readlane(__float_as_int(a), d + 1)), WBl[(d + 1) * D + lane], p1);
            p2 = fmaf(__int_as_float(__builtin_amdgcn_readlane(__float_as_int(a), d + 2)), WBl[(d + 2) * D + lane], p2);
            p3 = fmaf(__int_as_float(__builtin_amdgcn_readlane(__float_as_int(a), d + 3)), WBl[(d + 3) * D + lane], p3);
        }
        accv += (p0 + p1) + (p2 + p3);
    }

    if (MODE == 0 || MODE == 1) {
        hout[(size_t)wid * D + lane] = a;
        acc[(size_t)wid * D + lane]  = accv;
    } else if (MODE == 2) {
        float v = accv + bias[lane];
        float al = alpha[0];
        v = v >= 0.0f ? v : al * v;
        hout[(size_t)wid * D + lane] = v;   // act0
    } else {
        float v = accv + bias[lane];
        float al = alpha[0];
        v = v >= 0.0f ? v : al * v;
        v *= Wout[lane];
#pragma unroll
        for (int st = 32; st > 0; st >>= 1) v += __shfl_down(v, st, 64);
        if (lane == 0) nscal[wid] = v;
    }
}

// ---------------- segment-sum of per-node scalars into 128 graph bins ----------------

__global__ void init_out_kernel(float* __restrict__ out, const float* __restrict__ bout, int n) {
    int i = threadIdx.x;
    if (i < n) out[i] = bout[0];
}

#define SEG_BLOCKS 128

__global__ void segsum_kernel(const float* __restrict__ s, const int* __restrict__ batch,
                              float* __restrict__ out, int N) {
    __shared__ float bins[GRAPHS];
    for (int i = threadIdx.x; i < GRAPHS; i += 256) bins[i] = 0.0f;
    __syncthreads();
    int chunk = (N + SEG_BLOCKS - 1) / SEG_BLOCKS;
    int lo = blockIdx.x * chunk;
    int hi = min(lo + chunk, N);
    for (int i = lo + threadIdx.x; i < hi; i += 256)
        atomicAdd(&bins[batch[i]], s[i]);
    __syncthreads();
    for (int g = threadIdx.x; g < GRAPHS; g += 256) {
        float v = bins[g];
        if (v != 0.0f) atomicAdd(&out[g], v);
    }
}

extern "C" void kernel_launch(void* const* d_in, const int* in_sizes, int n_in,
                              void* d_out, int out_size, void* d_ws, size_t ws_size,
                              hipStream_t stream) {
    const float* x     = (const float*)d_in[0];
    const int*   ei    = (const int*)d_in[1];
    const int*   batch = (const int*)d_in[2];
    const float* W0    = (const float*)d_in[3];
    const float* b0    = (const float*)d_in[4];
    const float* W1    = (const float*)d_in[5];
    const float* b1    = (const float*)d_in[6];
    const float* a0    = (const float*)d_in[7];
    const float* a1    = (const float*)d_in[8];
    const float* Wout  = (const float*)d_in[9];
    const float* bout  = (const float*)d_in[10];

    const int N = in_sizes[0] / D;
    const int E = in_sizes[1] / 2;
    const int* src = ei;
    const int* dst = ei + E;

    size_t off = 0;
    auto alloc = [&](size_t bytes) -> void* {
        void* p = (char*)d_ws + off;
        off = (off + bytes + 255) & ~(size_t)255;
        return p;
    };
    const int NB = (N + 255) / 256;
    int*   deg      = (int*)alloc((size_t)N * 4);
    int*   rowstart = (int*)alloc((size_t)N * 4);
    int*   cursor   = (int*)alloc((size_t)N * 4);
    float* dinv     = (float*)alloc((size_t)N * 4);
    int*   bsum     = (int*)alloc((size_t)NB * 4);
    int*   boff     = (int*)alloc((size_t)NB * 4);
    int2*  epack    = (int2*)alloc((size_t)E * 8);
    float* hA       = (float*)alloc((size_t)N * D * 4);
    float* hB       = (float*)alloc((size_t)N * D * 4);
    float* acc      = (float*)alloc((size_t)N * D * 4);
    float* act0     = (float*)alloc((size_t)N * D * 4);
    float* nscal    = (float*)alloc((size_t)N * 4);

    const int EB = (E + 255) / 256;
    const int NP = (N + ROWS_PER_BLOCK - 1) / ROWS_PER_BLOCK;  // fused-prop blocks (1024 thr)
    const size_t LDS1 = D * D * 4;       // 16 KB (one W)
    const size_t LDS2 = 2 * D * D * 4;   // 32 KB (two W)

    // --- gcn_norm + CSR build ---
    hipMemsetAsync(deg, 0, (size_t)N * 4, stream);
    deg_kernel<<<EB, 256, 0, stream>>>(dst, deg, E);
    dinv_kernel<<<NB, 256, 0, stream>>>(deg, dinv, N);
    block_sum_kernel<<<NB, 256, 0, stream>>>(deg, bsum, N);
    scan_bsum_kernel<<<1, 256, 0, stream>>>(bsum, boff, NB);
    block_scan_kernel<<<NB, 256, 0, stream>>>(deg, boff, rowstart, cursor, N);
    scatter_kernel<<<EB, 256, 0, stream>>>(src, dst, dinv, cursor, epack, E);

    // --- layer 0: TAGConv(x; W0,b0) + PReLU(a0) -> act0 ---
    prop_fused_kernel<0><<<NP, 1024, LDS2, stream>>>(x,  hA, acc, W0, W0 + 1 * D * D,
        nullptr, nullptr, nullptr, nullptr, rowstart, deg, epack, N);
    prop_fused_kernel<1><<<NP, 1024, LDS1, stream>>>(hA, hB, acc, nullptr, W0 + 2 * D * D,
        nullptr, nullptr, nullptr, nullptr, rowstart, deg, epack, N);
    prop_fused_kernel<2><<<NP, 1024, LDS1, stream>>>(hB, act0, acc, nullptr, W0 + 3 * D * D,
        b0, a0, nullptr, nullptr, rowstart, deg, epack, N);

    // --- layer 1: TAGConv(act0; W1,b1) + PReLU(a1) + Wout-dot -> nscal ---
    prop_fused_kernel<0><<<NP, 1024, LDS2, stream>>>(act0, hA, acc, W1, W1 + 1 * D * D,
        nullptr, nullptr, nullptr, nullptr, rowstart, deg, epack, N);
    prop_fused_kernel<1><<<NP, 1024, LDS1, stream>>>(hA, hB, acc, nullptr, W1 + 2 * D * D,
        nullptr, nullptr, nullptr, nullptr, rowstart, deg, epack, N);
    prop_fused_kernel<3><<<NP, 1024, LDS1, stream>>>(hB, nullptr, acc, nullptr, W1 + 3 * D * D,
        b1, a1, Wout, nscal, rowstart, deg, epack, N);

    // --- global_add_pool (two-stage, contention-free) ---
    init_out_kernel<<<1, 128, 0, stream>>>((float*)d_out, bout, out_size);
    segsum_kernel<<<SEG_BLOCKS, 256, 0, stream>>>(nscal, batch, (float*)d_out, N);
}

// Round 4
// 488.816 us; speedup vs baseline: 2.4183x; 1.3114x over previous
//
#include <hip/hip_runtime.h>
#include <hip/hip_bf16.h>

#define D 64          // feature dim == hidden dim
#define GRAPHS 128

// ---------------- small helpers ----------------

__device__ __forceinline__ float bf2f(unsigned short u) {
    return __uint_as_float(((unsigned)u) << 16);
}
__device__ __forceinline__ unsigned short f2bf(float f) {
    unsigned u = __float_as_uint(f);
    unsigned r = (u + 0x7FFFu + ((u >> 16) & 1u)) >> 16;   // RNE
    return (unsigned short)r;
}
__device__ __forceinline__ float bcast(float v, int l) {
    return __int_as_float(__builtin_amdgcn_readlane(__float_as_int(v), l));
}

// ---------------- gcn_norm / CSR build ----------------

__global__ void deg_kernel(const int* __restrict__ dst, int* __restrict__ deg, int E) {
    int e = blockIdx.x * blockDim.x + threadIdx.x;
    if (e < E) atomicAdd(&deg[dst[e]], 1);
}

__global__ void dinv_kernel(const int* __restrict__ deg, float* __restrict__ dinv, int N) {
    int i = blockIdx.x * blockDim.x + threadIdx.x;
    if (i < N) {
        int d = deg[i];
        dinv[i] = d > 0 ? rsqrtf((float)d) : 0.0f;
    }
}

__global__ void block_sum_kernel(const int* __restrict__ deg, int* __restrict__ bsum, int N) {
    __shared__ int s[256];
    int i = blockIdx.x * 256 + threadIdx.x;
    s[threadIdx.x] = (i < N) ? deg[i] : 0;
    __syncthreads();
    for (int st = 128; st > 0; st >>= 1) {
        if (threadIdx.x < st) s[threadIdx.x] += s[threadIdx.x + st];
        __syncthreads();
    }
    if (threadIdx.x == 0) bsum[blockIdx.x] = s[0];
}

__global__ void scan_bsum_kernel(const int* __restrict__ bsum, int* __restrict__ boff, int NB) {
    if (NB <= 256) {
        __shared__ int s[256];
        int i = threadIdx.x;
        int v = (i < NB) ? bsum[i] : 0;
        s[i] = v;
        __syncthreads();
        for (int st = 1; st < 256; st <<= 1) {
            int add = (i >= st) ? s[i - st] : 0;
            __syncthreads();
            s[i] += add;
            __syncthreads();
        }
        if (i < NB) boff[i] = s[i] - v;
    } else if (threadIdx.x == 0) {
        int run = 0;
        for (int i = 0; i < NB; ++i) { boff[i] = run; run += bsum[i]; }
    }
}

__global__ void block_scan_kernel(const int* __restrict__ deg, const int* __restrict__ boff,
                                  int* __restrict__ rowstart, int* __restrict__ cursor, int N) {
    __shared__ int s[256];
    int i = blockIdx.x * 256 + threadIdx.x;
    int v = (i < N) ? deg[i] : 0;
    s[threadIdx.x] = v;
    __syncthreads();
    for (int st = 1; st < 256; st <<= 1) {
        int add = (threadIdx.x >= st) ? s[threadIdx.x - st] : 0;
        __syncthreads();
        s[threadIdx.x] += add;
        __syncthreads();
    }
    if (i < N) {
        int excl = boff[blockIdx.x] + s[threadIdx.x] - v;
        rowstart[i] = excl;
        cursor[i]   = excl;
    }
}

__global__ void scatter_kernel(const int* __restrict__ src, const int* __restrict__ dst,
                               const float* __restrict__ dinv, int* __restrict__ cursor,
                               int2* __restrict__ ep, int E) {
    int e = blockIdx.x * blockDim.x + threadIdx.x;
    if (e < E) {
        int d = dst[e], s = src[e];
        float w = dinv[s] * dinv[d];
        int pos = atomicAdd(&cursor[d], 1);
        int2 pk; pk.x = s; pk.y = __float_as_int(w);
        ep[pos] = pk;
    }
}

// ---------------- fused propagation + GEMM epilogue ----------------
// Wave per dst node, lane = feature. h rows stored bf16 (halves gather bytes +
// L2 footprint); acc stays fp32. Gather is 4-deep software-pipelined: 4 loads
// in flight per wave, 4 independent accumulators.
// MODE: 0 first hop (acc = own@WA + h@WB), 1 middle hop (acc += h@WB),
//       2 last hop layer0 (act0 = prelu(acc + h@WB + b)),
//       3 last hop layer1 (nscal = prelu(acc + h@WB + b)·Wout).
// INF:  0 = `in` rows are fp32 (layer-0 first hop reads x), 1 = bf16 rows.

#define ROWS_PER_BLOCK 8    // 512 threads -> 4 blocks/CU (LDS 16/32 KB, VGPR<=64)

__device__ __forceinline__ float apply_w(float vec, const float* __restrict__ Wl, int lane) {
    float p0 = 0.f, p1 = 0.f, p2 = 0.f, p3 = 0.f;
#pragma unroll
    for (int d = 0; d < D; d += 4) {
        p0 = fmaf(bcast(vec, d + 0), Wl[(d + 0) * D + lane], p0);
        p1 = fmaf(bcast(vec, d + 1), Wl[(d + 1) * D + lane], p1);
        p2 = fmaf(bcast(vec, d + 2), Wl[(d + 2) * D + lane], p2);
        p3 = fmaf(bcast(vec, d + 3), Wl[(d + 3) * D + lane], p3);
    }
    return (p0 + p1) + (p2 + p3);
}

template<int MODE, int INF>
__global__ __launch_bounds__(512, 8)
void prop_fused_kernel(const void* __restrict__ in_v, void* __restrict__ hout_v,
                       float* __restrict__ acc,
                       const float* __restrict__ WA, const float* __restrict__ WB,
                       const float* __restrict__ bias, const float* __restrict__ alpha,
                       const float* __restrict__ Wout, float* __restrict__ nscal,
                       const int* __restrict__ rowstart, const int* __restrict__ deg,
                       const int2* __restrict__ ep, int N) {
    extern __shared__ float smem[];
    float* WBl = smem;
    float* WAl = smem + D * D;

    for (int i = threadIdx.x; i < D * D; i += blockDim.x) WBl[i] = WB[i];
    if (MODE == 0)
        for (int i = threadIdx.x; i < D * D; i += blockDim.x) WAl[i] = WA[i];
    __syncthreads();

    int wid = blockIdx.x * ROWS_PER_BLOCK + (threadIdx.x >> 6);
    if (wid >= N) return;
    int lane = threadIdx.x & 63;

    const float*          inF  = (const float*)in_v;
    const unsigned short* in16 = (const unsigned short*)in_v;

    int start = __builtin_amdgcn_readfirstlane(rowstart[wid]);
    int cnt   = __builtin_amdgcn_readfirstlane(deg[wid]);

    // ---- gather: cooperative edge load, 4-deep pipelined row gathers ----
    float a0 = 0.f, a1 = 0.f, a2 = 0.f, a3 = 0.f;
    for (int base = 0; base < cnt; base += 64) {
        int m = min(cnt - base, 64);
        int2 e = make_int2(0, 0);
        if (lane < m) e = ep[start + base + lane];
        int i = 0;
        for (; i + 4 <= m; i += 4) {
            int s0 = __builtin_amdgcn_readlane(e.x, i + 0);
            int s1 = __builtin_amdgcn_readlane(e.x, i + 1);
            int s2 = __builtin_amdgcn_readlane(e.x, i + 2);
            int s3 = __builtin_amdgcn_readlane(e.x, i + 3);
            float f0, f1, f2, f3;
            if (INF == 0) {
                f0 = inF[(size_t)s0 * D + lane];
                f1 = inF[(size_t)s1 * D + lane];
                f2 = inF[(size_t)s2 * D + lane];
                f3 = inF[(size_t)s3 * D + lane];
            } else {
                f0 = bf2f(in16[(size_t)s0 * D + lane]);
                f1 = bf2f(in16[(size_t)s1 * D + lane]);
                f2 = bf2f(in16[(size_t)s2 * D + lane]);
                f3 = bf2f(in16[(size_t)s3 * D + lane]);
            }
            a0 = fmaf(__int_as_float(__builtin_amdgcn_readlane(e.y, i + 0)), f0, a0);
            a1 = fmaf(__int_as_float(__builtin_amdgcn_readlane(e.y, i + 1)), f1, a1);
            a2 = fmaf(__int_as_float(__builtin_amdgcn_readlane(e.y, i + 2)), f2, a2);
            a3 = fmaf(__int_as_float(__builtin_amdgcn_readlane(e.y, i + 3)), f3, a3);
        }
        for (; i < m; ++i) {
            int sidx = __builtin_amdgcn_readlane(e.x, i);
            float f = (INF == 0) ? inF[(size_t)sidx * D + lane]
                                 : bf2f(in16[(size_t)sidx * D + lane]);
            a0 = fmaf(__int_as_float(__builtin_amdgcn_readlane(e.y, i)), f, a0);
        }
    }
    float a = (a0 + a1) + (a2 + a3);

    // ---- epilogue ----
    float accv;
    if (MODE == 0) {
        float own = (INF == 0) ? inF[(size_t)wid * D + lane]
                               : bf2f(in16[(size_t)wid * D + lane]);
        accv = apply_w(own, WAl, lane);
    } else {
        accv = acc[(size_t)wid * D + lane];
    }
    accv += apply_w(a, WBl, lane);

    if (MODE == 0 || MODE == 1) {
        ((unsigned short*)hout_v)[(size_t)wid * D + lane] = f2bf(a);
        acc[(size_t)wid * D + lane] = accv;
    } else if (MODE == 2) {
        float v = accv + bias[lane];
        float al = alpha[0];
        v = v >= 0.0f ? v : al * v;
        ((unsigned short*)hout_v)[(size_t)wid * D + lane] = f2bf(v);   // act0 (bf16)
    } else {
        float v = accv + bias[lane];
        float al = alpha[0];
        v = v >= 0.0f ? v : al * v;
        v *= Wout[lane];
#pragma unroll
        for (int st = 32; st > 0; st >>= 1) v += __shfl_down(v, st, 64);
        if (lane == 0) nscal[wid] = v;
    }
}

// ---------------- segment-sum + output init ----------------

__global__ void init_out_kernel(float* __restrict__ out, const float* __restrict__ bout, int n) {
    int i = threadIdx.x;
    if (i < n) out[i] = bout[0];
}

#define SEG_BLOCKS 128

__global__ void segsum_kernel(const float* __restrict__ s, const int* __restrict__ batch,
                              float* __restrict__ out, int N) {
    __shared__ float bins[GRAPHS];
    for (int i = threadIdx.x; i < GRAPHS; i += 256) bins[i] = 0.0f;
    __syncthreads();
    int chunk = (N + SEG_BLOCKS - 1) / SEG_BLOCKS;
    int lo = blockIdx.x * chunk;
    int hi = min(lo + chunk, N);
    for (int i = lo + threadIdx.x; i < hi; i += 256)
        atomicAdd(&bins[batch[i]], s[i]);
    __syncthreads();
    for (int g = threadIdx.x; g < GRAPHS; g += 256) {
        float v = bins[g];
        if (v != 0.0f) atomicAdd(&out[g], v);
    }
}

extern "C" void kernel_launch(void* const* d_in, const int* in_sizes, int n_in,
                              void* d_out, int out_size, void* d_ws, size_t ws_size,
                              hipStream_t stream) {
    const float* x     = (const float*)d_in[0];
    const int*   ei    = (const int*)d_in[1];
    const int*   batch = (const int*)d_in[2];
    const float* W0    = (const float*)d_in[3];
    const float* b0    = (const float*)d_in[4];
    const float* W1    = (const float*)d_in[5];
    const float* b1    = (const float*)d_in[6];
    const float* a0    = (const float*)d_in[7];
    const float* a1    = (const float*)d_in[8];
    const float* Wout  = (const float*)d_in[9];
    const float* bout  = (const float*)d_in[10];

    const int N = in_sizes[0] / D;
    const int E = in_sizes[1] / 2;
    const int* src = ei;
    const int* dst = ei + E;

    size_t off = 0;
    auto alloc = [&](size_t bytes) -> void* {
        void* p = (char*)d_ws + off;
        off = (off + bytes + 255) & ~(size_t)255;
        return p;
    };
    const int NB = (N + 255) / 256;
    int*   deg      = (int*)alloc((size_t)N * 4);
    int*   rowstart = (int*)alloc((size_t)N * 4);
    int*   cursor   = (int*)alloc((size_t)N * 4);
    float* dinv     = (float*)alloc((size_t)N * 4);
    int*   bsum     = (int*)alloc((size_t)NB * 4);
    int*   boff     = (int*)alloc((size_t)NB * 4);
    int2*  epack    = (int2*)alloc((size_t)E * 8);
    unsigned short* hA   = (unsigned short*)alloc((size_t)N * D * 2);  // bf16 rows
    unsigned short* hB   = (unsigned short*)alloc((size_t)N * D * 2);
    unsigned short* act0 = (unsigned short*)alloc((size_t)N * D * 2);
    float* acc      = (float*)alloc((size_t)N * D * 4);
    float* nscal    = (float*)alloc((size_t)N * 4);

    const int EB = (E + 255) / 256;
    const int NP = (N + ROWS_PER_BLOCK - 1) / ROWS_PER_BLOCK;  // 512-thread blocks
    const size_t LDS1 = D * D * 4;       // 16 KB
    const size_t LDS2 = 2 * D * D * 4;   // 32 KB

    // --- gcn_norm + CSR build ---
    hipMemsetAsync(deg, 0, (size_t)N * 4, stream);
    deg_kernel<<<EB, 256, 0, stream>>>(dst, deg, E);
    dinv_kernel<<<NB, 256, 0, stream>>>(deg, dinv, N);
    block_sum_kernel<<<NB, 256, 0, stream>>>(deg, bsum, N);
    scan_bsum_kernel<<<1, 256, 0, stream>>>(bsum, boff, NB);
    block_scan_kernel<<<NB, 256, 0, stream>>>(deg, boff, rowstart, cursor, N);
    scatter_kernel<<<EB, 256, 0, stream>>>(src, dst, dinv, cursor, epack, E);

    // --- layer 0: TAGConv(x; W0,b0) + PReLU(a0) -> act0 (bf16) ---
    prop_fused_kernel<0, 0><<<NP, 512, LDS2, stream>>>(x,  hA, acc, W0, W0 + 1 * D * D,
        nullptr, nullptr, nullptr, nullptr, rowstart, deg, epack, N);
    prop_fused_kernel<1, 1><<<NP, 512, LDS1, stream>>>(hA, hB, acc, nullptr, W0 + 2 * D * D,
        nullptr, nullptr, nullptr, nullptr, rowstart, deg, epack, N);
    prop_fused_kernel<2, 1><<<NP, 512, LDS1, stream>>>(hB, act0, acc, nullptr, W0 + 3 * D * D,
        b0, a0, nullptr, nullptr, rowstart, deg, epack, N);

    // --- layer 1: TAGConv(act0; W1,b1) + PReLU(a1) + Wout-dot -> nscal ---
    prop_fused_kernel<0, 1><<<NP, 512, LDS2, stream>>>(act0, hA, acc, W1, W1 + 1 * D * D,
        nullptr, nullptr, nullptr, nullptr, rowstart, deg, epack, N);
    prop_fused_kernel<1, 1><<<NP, 512, LDS1, stream>>>(hA, hB, acc, nullptr, W1 + 2 * D * D,
        nullptr, nullptr, nullptr, nullptr, rowstart, deg, epack, N);
    prop_fused_kernel<3, 1><<<NP, 512, LDS1, stream>>>(hB, nullptr, acc, nullptr, W1 + 3 * D * D,
        b1, a1, Wout, nscal, rowstart, deg, epack, N);

    // --- global_add_pool (two-stage, contention-free) ---
    init_out_kernel<<<1, 128, 0, stream>>>((float*)d_out, bout, out_size);
    segsum_kernel<<<SEG_BLOCKS, 256, 0, stream>>>(nscal, batch, (float*)d_out, N);
}

// Round 5
// 332.791 us; speedup vs baseline: 3.5521x; 1.4688x over previous
//
#include <hip/hip_runtime.h>
#include <hip/hip_bf16.h>

#define D 64
#define GRAPHS 128

using bf16x8 = __attribute__((ext_vector_type(8))) short;   // 8 bf16 (4 VGPRs)
using f32x4  = __attribute__((ext_vector_type(4))) float;

// ---------------- small helpers ----------------

__device__ __forceinline__ float bf2f(unsigned short u) {
    return __uint_as_float(((unsigned)u) << 16);
}
__device__ __forceinline__ unsigned short f2bf(float f) {
    unsigned u = __float_as_uint(f);
    unsigned r = (u + 0x7FFFu + ((u >> 16) & 1u)) >> 16;   // RNE
    return (unsigned short)r;
}

// ---------------- gcn_norm / CSR build ----------------

__global__ void deg_kernel(const int* __restrict__ dst, int* __restrict__ deg, int E) {
    int e = blockIdx.x * blockDim.x + threadIdx.x;
    if (e < E) atomicAdd(&deg[dst[e]], 1);
}

__global__ void dinv_kernel(const int* __restrict__ deg, float* __restrict__ dinv, int N) {
    int i = blockIdx.x * blockDim.x + threadIdx.x;
    if (i < N) {
        int d = deg[i];
        dinv[i] = d > 0 ? rsqrtf((float)d) : 0.0f;
    }
}

__global__ void block_sum_kernel(const int* __restrict__ deg, int* __restrict__ bsum, int N) {
    __shared__ int s[256];
    int i = blockIdx.x * 256 + threadIdx.x;
    s[threadIdx.x] = (i < N) ? deg[i] : 0;
    __syncthreads();
    for (int st = 128; st > 0; st >>= 1) {
        if (threadIdx.x < st) s[threadIdx.x] += s[threadIdx.x + st];
        __syncthreads();
    }
    if (threadIdx.x == 0) bsum[blockIdx.x] = s[0];
}

__global__ void scan_bsum_kernel(const int* __restrict__ bsum, int* __restrict__ boff, int NB) {
    if (NB <= 256) {
        __shared__ int s[256];
        int i = threadIdx.x;
        int v = (i < NB) ? bsum[i] : 0;
        s[i] = v;
        __syncthreads();
        for (int st = 1; st < 256; st <<= 1) {
            int add = (i >= st) ? s[i - st] : 0;
            __syncthreads();
            s[i] += add;
            __syncthreads();
        }
        if (i < NB) boff[i] = s[i] - v;
    } else if (threadIdx.x == 0) {
        int run = 0;
        for (int i = 0; i < NB; ++i) { boff[i] = run; run += bsum[i]; }
    }
}

__global__ void block_scan_kernel(const int* __restrict__ deg, const int* __restrict__ boff,
                                  int* __restrict__ rowstart, int* __restrict__ cursor, int N) {
    __shared__ int s[256];
    int i = blockIdx.x * 256 + threadIdx.x;
    int v = (i < N) ? deg[i] : 0;
    s[threadIdx.x] = v;
    __syncthreads();
    for (int st = 1; st < 256; st <<= 1) {
        int add = (threadIdx.x >= st) ? s[threadIdx.x - st] : 0;
        __syncthreads();
        s[threadIdx.x] += add;
        __syncthreads();
    }
    if (i < N) {
        int excl = boff[blockIdx.x] + s[threadIdx.x] - v;
        rowstart[i] = excl;
        cursor[i]   = excl;
    }
}

__global__ void scatter_kernel(const int* __restrict__ src, const int* __restrict__ dst,
                               const float* __restrict__ dinv, int* __restrict__ cursor,
                               int2* __restrict__ ep, int E) {
    int e = blockIdx.x * blockDim.x + threadIdx.x;
    if (e < E) {
        int d = dst[e], s = src[e];
        float w = dinv[s] * dinv[d];
        int pos = atomicAdd(&cursor[d], 1);
        int2 pk; pk.x = s; pk.y = __float_as_int(w);
        ep[pos] = pk;
    }
}

// ---------------- x -> bf16 into H slot 0 ----------------

__global__ void xcvt_kernel(const float* __restrict__ x, unsigned short* __restrict__ H, int total) {
    int i = blockIdx.x * blockDim.x + threadIdx.x;
    if (i < total) {
        int n = i >> 6, f = i & 63;
        H[(size_t)n * 256 + f] = f2bf(x[i]);
    }
}

// ---------------- pure gather: out_row = sum_e w_e * in_row[src_e] ----------------
// Wave per dst node, lane = feature. Edge list reads are wave-uniform -> SMEM
// (s_load) pipe; weight stays SGPR (v_fmac src0); row gathers are saddr-form.
// 8-deep pipeline: 8 independent accumulators / 8 loads in flight.

#define GROWS 8   // 512 threads/block

__global__ __launch_bounds__(512, 8)
void gather_kernel(const unsigned short* __restrict__ in,   // H + slot_in*64
                   unsigned short* __restrict__ out,        // H + slot_out*64
                   const int* __restrict__ rowstart, const int* __restrict__ deg,
                   const int2* __restrict__ ep, int N) {
    int wid = blockIdx.x * GROWS + (threadIdx.x >> 6);
    if (wid >= N) return;
    int lane = threadIdx.x & 63;

    int start = __builtin_amdgcn_readfirstlane(rowstart[wid]);
    int cnt   = __builtin_amdgcn_readfirstlane(deg[wid]);

    float a0 = 0.f, a1 = 0.f, a2 = 0.f, a3 = 0.f, a4 = 0.f, a5 = 0.f, a6 = 0.f, a7 = 0.f;
    int i = 0;
    for (; i + 8 <= cnt; i += 8) {
        int2 e0 = ep[start + i + 0];
        int2 e1 = ep[start + i + 1];
        int2 e2 = ep[start + i + 2];
        int2 e3 = ep[start + i + 3];
        int2 e4 = ep[start + i + 4];
        int2 e5 = ep[start + i + 5];
        int2 e6 = ep[start + i + 6];
        int2 e7 = ep[start + i + 7];
        float f0 = bf2f(in[(size_t)(unsigned)e0.x * 256 + lane]);
        float f1 = bf2f(in[(size_t)(unsigned)e1.x * 256 + lane]);
        float f2 = bf2f(in[(size_t)(unsigned)e2.x * 256 + lane]);
        float f3 = bf2f(in[(size_t)(unsigned)e3.x * 256 + lane]);
        float f4 = bf2f(in[(size_t)(unsigned)e4.x * 256 + lane]);
        float f5 = bf2f(in[(size_t)(unsigned)e5.x * 256 + lane]);
        float f6 = bf2f(in[(size_t)(unsigned)e6.x * 256 + lane]);
        float f7 = bf2f(in[(size_t)(unsigned)e7.x * 256 + lane]);
        a0 = fmaf(__int_as_float(e0.y), f0, a0);
        a1 = fmaf(__int_as_float(e1.y), f1, a1);
        a2 = fmaf(__int_as_float(e2.y), f2, a2);
        a3 = fmaf(__int_as_float(e3.y), f3, a3);
        a4 = fmaf(__int_as_float(e4.y), f4, a4);
        a5 = fmaf(__int_as_float(e5.y), f5, a5);
        a6 = fmaf(__int_as_float(e6.y), f6, a6);
        a7 = fmaf(__int_as_float(e7.y), f7, a7);
    }
    for (; i + 4 <= cnt; i += 4) {
        int2 e0 = ep[start + i + 0];
        int2 e1 = ep[start + i + 1];
        int2 e2 = ep[start + i + 2];
        int2 e3 = ep[start + i + 3];
        a0 = fmaf(__int_as_float(e0.y), bf2f(in[(size_t)(unsigned)e0.x * 256 + lane]), a0);
        a1 = fmaf(__int_as_float(e1.y), bf2f(in[(size_t)(unsigned)e1.x * 256 + lane]), a1);
        a2 = fmaf(__int_as_float(e2.y), bf2f(in[(size_t)(unsigned)e2.x * 256 + lane]), a2);
        a3 = fmaf(__int_as_float(e3.y), bf2f(in[(size_t)(unsigned)e3.x * 256 + lane]), a3);
    }
    for (; i < cnt; ++i) {
        int2 e0 = ep[start + i];
        a0 = fmaf(__int_as_float(e0.y), bf2f(in[(size_t)(unsigned)e0.x * 256 + lane]), a0);
    }
    float a = ((a0 + a1) + (a2 + a3)) + ((a4 + a5) + (a6 + a7));
    out[(size_t)wid * 256 + lane] = f2bf(a);
}

// ---------------- W -> per-lane MFMA B-fragment layout (bf16) ----------------
// Wfrag[kt][ct][lane][j]: B[k= kt*32 + (lane>>4)*8 + j][n= ct*16 + (lane&15)]
// so each lane's 8 B-elements are one coalesced 16B global load.

__global__ void wfrag_kernel(const float* __restrict__ W, unsigned short* __restrict__ Wfrag) {
    int i = blockIdx.x * 256 + threadIdx.x;   // total 8*4*64*8 = 16384
    if (i >= 16384) return;
    int j = i & 7, lane = (i >> 3) & 63, ct = (i >> 9) & 3, kt = i >> 11;
    int n = ct * 16 + (lane & 15);
    int k = kt * 32 + (lane >> 4) * 8 + j;
    Wfrag[i] = f2bf(W[k * 64 + n]);           // W viewed as [256][64]
}

// ---------------- layer projection: C[N x 64] = H[N x 256] @ Wflat[256 x 64] ----------------
// MFMA 16x16x32 bf16. Block 256 = 4 waves; wave handles 16 rows x 64 cols (4 tiles).
// MODE 2: act = prelu(C + b) -> bf16 into H2 slot 0.
// MODE 3: nscal[row] = sum_col prelu(C + b)[col] * Wout[col].

template<int MODE>
__global__ __launch_bounds__(256, 4)
void tag_gemm_kernel(const unsigned short* __restrict__ H,
                     const unsigned short* __restrict__ Wfrag,
                     const float* __restrict__ bias, const float* __restrict__ alpha,
                     const float* __restrict__ Wout,
                     unsigned short* __restrict__ H2, float* __restrict__ nscal, int N) {
    int w = threadIdx.x >> 6, lane = threadIdx.x & 63;
    int m = lane & 15, quad = lane >> 4;
    int rowbase = blockIdx.x * 64 + w * 16;
    int arow = rowbase + m;
    size_t aoff = (size_t)min(arow, N - 1) * 256 + quad * 8;

    f32x4 acc0 = {0.f, 0.f, 0.f, 0.f}, acc1 = acc0, acc2 = acc0, acc3 = acc0;
#pragma unroll
    for (int kt = 0; kt < 8; ++kt) {
        bf16x8 A = *(const bf16x8*)(H + aoff + kt * 32);
        const unsigned short* wf = Wfrag + ((size_t)(kt * 4) * 64 + lane) * 8;
        bf16x8 B0 = *(const bf16x8*)(wf + 0 * 64 * 8);
        bf16x8 B1 = *(const bf16x8*)(wf + 1 * 64 * 8);
        bf16x8 B2 = *(const bf16x8*)(wf + 2 * 64 * 8);
        bf16x8 B3 = *(const bf16x8*)(wf + 3 * 64 * 8);
        acc0 = __builtin_amdgcn_mfma_f32_16x16x32_bf16(A, B0, acc0, 0, 0, 0);
        acc1 = __builtin_amdgcn_mfma_f32_16x16x32_bf16(A, B1, acc1, 0, 0, 0);
        acc2 = __builtin_amdgcn_mfma_f32_16x16x32_bf16(A, B2, acc2, 0, 0, 0);
        acc3 = __builtin_amdgcn_mfma_f32_16x16x32_bf16(A, B3, acc3, 0, 0, 0);
    }

    float al = alpha[0];
    f32x4 accs[4] = {acc0, acc1, acc2, acc3};
    if (MODE == 2) {
#pragma unroll
        for (int ct = 0; ct < 4; ++ct) {
            int col = ct * 16 + m;
            float b = bias[col];
#pragma unroll
            for (int r = 0; r < 4; ++r) {
                int row = rowbase + quad * 4 + r;
                if (row < N) {
                    float v = accs[ct][r] + b;
                    v = v >= 0.f ? v : al * v;
                    H2[(size_t)row * 256 + col] = f2bf(v);
                }
            }
        }
    } else {
        float rv0 = 0.f, rv1 = 0.f, rv2 = 0.f, rv3 = 0.f;
#pragma unroll
        for (int ct = 0; ct < 4; ++ct) {
            int col = ct * 16 + m;
            float b = bias[col], wo = Wout[col];
            float v;
            v = accs[ct][0] + b; v = v >= 0.f ? v : al * v; rv0 = fmaf(v, wo, rv0);
            v = accs[ct][1] + b; v = v >= 0.f ? v : al * v; rv1 = fmaf(v, wo, rv1);
            v = accs[ct][2] + b; v = v >= 0.f ? v : al * v; rv2 = fmaf(v, wo, rv2);
            v = accs[ct][3] + b; v = v >= 0.f ? v : al * v; rv3 = fmaf(v, wo, rv3);
        }
        float rv[4] = {rv0, rv1, rv2, rv3};
#pragma unroll
        for (int r = 0; r < 4; ++r) {
            float v = rv[r];
            v += __shfl_xor(v, 8, 16);
            v += __shfl_xor(v, 4, 16);
            v += __shfl_xor(v, 2, 16);
            v += __shfl_xor(v, 1, 16);
            int row = rowbase + quad * 4 + r;
            if (m == 0 && row < N) nscal[row] = v;
        }
    }
}

// ---------------- segment-sum + output init ----------------

__global__ void init_out_kernel(float* __restrict__ out, const float* __restrict__ bout, int n) {
    int i = threadIdx.x;
    if (i < n) out[i] = bout[0];
}

#define SEG_BLOCKS 128

__global__ void segsum_kernel(const float* __restrict__ s, const int* __restrict__ batch,
                              float* __restrict__ out, int N) {
    __shared__ float bins[GRAPHS];
    for (int i = threadIdx.x; i < GRAPHS; i += 256) bins[i] = 0.0f;
    __syncthreads();
    int chunk = (N + SEG_BLOCKS - 1) / SEG_BLOCKS;
    int lo = blockIdx.x * chunk;
    int hi = min(lo + chunk, N);
    for (int i = lo + threadIdx.x; i < hi; i += 256)
        atomicAdd(&bins[batch[i]], s[i]);
    __syncthreads();
    for (int g = threadIdx.x; g < GRAPHS; g += 256) {
        float v = bins[g];
        if (v != 0.0f) atomicAdd(&out[g], v);
    }
}

extern "C" void kernel_launch(void* const* d_in, const int* in_sizes, int n_in,
                              void* d_out, int out_size, void* d_ws, size_t ws_size,
                              hipStream_t stream) {
    const float* x     = (const float*)d_in[0];
    const int*   ei    = (const int*)d_in[1];
    const int*   batch = (const int*)d_in[2];
    const float* W0    = (const float*)d_in[3];
    const float* b0    = (const float*)d_in[4];
    const float* W1    = (const float*)d_in[5];
    const float* b1    = (const float*)d_in[6];
    const float* a0    = (const float*)d_in[7];
    const float* a1    = (const float*)d_in[8];
    const float* Wout  = (const float*)d_in[9];
    const float* bout  = (const float*)d_in[10];

    const int N = in_sizes[0] / D;
    const int E = in_sizes[1] / 2;
    const int* src = ei;
    const int* dst = ei + E;

    size_t off = 0;
    auto alloc = [&](size_t bytes) -> void* {
        void* p = (char*)d_ws + off;
        off = (off + bytes + 255) & ~(size_t)255;
        return p;
    };
    const int NB = (N + 255) / 256;
    int*   deg      = (int*)alloc((size_t)N * 4);
    int*   rowstart = (int*)alloc((size_t)N * 4);
    int*   cursor   = (int*)alloc((size_t)N * 4);
    float* dinv     = (float*)alloc((size_t)N * 4);
    int*   bsum     = (int*)alloc((size_t)NB * 4);
    int*   boff     = (int*)alloc((size_t)NB * 4);
    int2*  epack    = (int2*)alloc((size_t)E * 8);
    unsigned short* HA = (unsigned short*)alloc((size_t)N * 256 * 2);  // [N][4][64] bf16
    unsigned short* HB = (unsigned short*)alloc((size_t)N * 256 * 2);
    unsigned short* WF0 = (unsigned short*)alloc(16384 * 2);
    unsigned short* WF1 = (unsigned short*)alloc(16384 * 2);
    float* nscal    = (float*)alloc((size_t)N * 4);

    const int EB = (E + 255) / 256;
    const int NG = (N + GROWS - 1) / GROWS;      // gather blocks (512 thr)
    const int NM = (N + 63) / 64;                // gemm blocks (256 thr)

    // --- gcn_norm + CSR build + weight prep ---
    hipMemsetAsync(deg, 0, (size_t)N * 4, stream);
    deg_kernel<<<EB, 256, 0, stream>>>(dst, deg, E);
    dinv_kernel<<<NB, 256, 0, stream>>>(deg, dinv, N);
    block_sum_kernel<<<NB, 256, 0, stream>>>(deg, bsum, N);
    scan_bsum_kernel<<<1, 256, 0, stream>>>(bsum, boff, NB);
    block_scan_kernel<<<NB, 256, 0, stream>>>(deg, boff, rowstart, cursor, N);
    scatter_kernel<<<EB, 256, 0, stream>>>(src, dst, dinv, cursor, epack, E);
    wfrag_kernel<<<64, 256, 0, stream>>>(W0, WF0);
    wfrag_kernel<<<64, 256, 0, stream>>>(W1, WF1);
    xcvt_kernel<<<(N * D + 255) / 256, 256, 0, stream>>>(x, HA, N * D);

    // --- layer 0: gathers fill HA slots 1..3, then fused GEMM+bias+PReLU -> HB slot 0 ---
    gather_kernel<<<NG, 512, 0, stream>>>(HA + 0 * 64, HA + 1 * 64, rowstart, deg, epack, N);
    gather_kernel<<<NG, 512, 0, stream>>>(HA + 1 * 64, HA + 2 * 64, rowstart, deg, epack, N);
    gather_kernel<<<NG, 512, 0, stream>>>(HA + 2 * 64, HA + 3 * 64, rowstart, deg, epack, N);
    tag_gemm_kernel<2><<<NM, 256, 0, stream>>>(HA, WF0, b0, a0, nullptr, HB, nullptr, N);

    // --- layer 1: gathers fill HB slots 1..3, then fused GEMM+bias+PReLU+Wout-dot -> nscal ---
    gather_kernel<<<NG, 512, 0, stream>>>(HB + 0 * 64, HB + 1 * 64, rowstart, deg, epack, N);
    gather_kernel<<<NG, 512, 0, stream>>>(HB + 1 * 64, HB + 2 * 64, rowstart, deg, epack, N);
    gather_kernel<<<NG, 512, 0, stream>>>(HB + 2 * 64, HB + 3 * 64, rowstart, deg, epack, N);
    tag_gemm_kernel<3><<<NM, 256, 0, stream>>>(HB, WF1, b1, a1, Wout, nullptr, nscal, N);

    // --- global_add_pool (two-stage, contention-free) ---
    init_out_kernel<<<1, 128, 0, stream>>>((float*)d_out, bout, out_size);
    segsum_kernel<<<SEG_BLOCKS, 256, 0, stream>>>(nscal, batch, (float*)d_out, N);
}